// Round 1
// baseline (8154.203 us; speedup 1.0000x reference)
//
#include <hip/hip_runtime.h>
#include <hip/hip_bf16.h>

// RNNColorbot: 2-layer LSTM (H=1024) over T=128, B=512, D_IN=256, then
// gather at seqlen-1 and dense[1024x3]+relu.
//
// Strategy: per-timestep fused GEMM+LSTM-cell kernels (bf16 MFMA, fp32 cell
// state), weights repacked once per call into bf16 with gate-interleaved
// column order so each WG can do the cell update locally.

typedef __hip_bfloat16 bf16;
typedef __attribute__((ext_vector_type(8))) short bfrag8;   // 8 bf16 = 4 VGPRs
typedef __attribute__((ext_vector_type(4))) float accf4;    // MFMA accum

#define BATCH 512
#define TSTEPS 128
#define DIN 256
#define H 1024
#define NG 4096   // 4*H gate columns

__device__ __forceinline__ float sigm(float x) {
    return 1.0f / (1.0f + __expf(-x));
}
__device__ __forceinline__ float tanh_f(float x) {
    float a = fabsf(x);
    float e = __expf(-2.0f * a);
    float t = (1.0f - e) / (1.0f + e);
    return x < 0.0f ? -t : t;
}

// ---------------------------------------------------------------------------
// Repack [W;U] (fp32, K x 4096) -> Bp bf16 [KT][4096][64], with column perm:
//   new col n -> orig col ((n>>5)&3)*1024 + (n>>7)*32 + (n&31)
// so each 128-col N-tile = 32 h-cols x gates [i|f|g|o] in 32-col blocks.
// Inner dim is k%64 so a GEMM B-tile is contiguous and n-major in LDS.
// ---------------------------------------------------------------------------
__global__ void k_repack(const float* __restrict__ W, const float* __restrict__ U,
                         bf16* __restrict__ Bp, int KIN)
{
    __shared__ float tile[64][65];
    int kt = blockIdx.x, nt = blockIdx.y;
    int lane = threadIdx.x;     // 64 threads
    int n = nt * 64 + lane;
    int orig = ((n >> 5) & 3) * 1024 + (n >> 7) * 32 + (n & 31);
    for (int j = 0; j < 64; ++j) {
        int k = kt * 64 + j;
        float v = (k < KIN) ? W[(size_t)k * NG + orig]
                            : U[(size_t)(k - KIN) * NG + orig];
        tile[j][lane] = v;
    }
    __syncthreads();
    for (int p = 0; p < 8; ++p) {
        int nloc = p * 8 + (lane >> 3);
        int nn = nt * 64 + nloc;
        int ko = (lane & 7) * 8;
        alignas(16) unsigned short pk[8];
        #pragma unroll
        for (int jj = 0; jj < 8; ++jj) {
            bf16 hv = __float2bfloat16(tile[ko + jj][nloc]);
            pk[jj] = *(unsigned short*)&hv;
        }
        *(int4*)(Bp + ((size_t)kt * NG + nn) * 64 + ko) = *(int4*)pk;
    }
}

// ---------------------------------------------------------------------------
// Fused LSTM step: z = [x_t | h_prev] @ Bp + b ; cell update ; write h,c.
// Tile: 64 rows (batch) x 128 gate-cols per WG; 4 waves; 16x16x32 bf16 MFMA.
// Grid: dim3(32 ntiles, 8 rowgroups) -> blockIdx%8 spreads ntiles over XCDs.
// ---------------------------------------------------------------------------
template <bool FIRST, bool LAST>
__global__ __launch_bounds__(256) void k_step(
    const float* __restrict__ chars,   // FIRST: [512][128][256] fp32
    const bf16* __restrict__ A0,       // !FIRST: h1 of this step [512][1024]
    const bf16* __restrict__ Hprev,    // [512][1024]
    const bf16* __restrict__ Bp,       // [KT][4096][64]
    const float* __restrict__ bias,    // [4096] original gate order
    float* __restrict__ Cst,           // [512][1024] fp32 cell state
    bf16* __restrict__ Hout,           // [512][1024]
    const int* __restrict__ seqlen,    // LAST
    float* __restrict__ hidden,        // LAST: [512][1024] fp32
    int t)
{
    constexpr int KT = FIRST ? 20 : 32;     // K = 1280 / 2048
    __shared__ bf16 Alds[64][64];           // 8 KB   (rows x k)
    __shared__ bf16 Blds[128][64];          // 16 KB  (n-major x k)
    __shared__ float zlds[64][129];         // 32.25 KB epilogue exchange

    int tid = threadIdx.x;
    int wv = tid >> 6, lane = tid & 63;
    int ntile = blockIdx.x;                 // 0..31
    int b0 = blockIdx.y * 64;               // 0..448
    int n0 = ntile * 128;
    int mw = (wv & 1) * 32;
    int nw = (wv >> 1) * 64;

    const accf4 zero4 = {0.f, 0.f, 0.f, 0.f};
    accf4 acc[2][4];
    #pragma unroll
    for (int i = 0; i < 2; ++i)
        #pragma unroll
        for (int j = 0; j < 4; ++j) acc[i][j] = zero4;

    for (int kt = 0; kt < KT; ++kt) {
        int k0 = kt * 64;
        // ---- stage A tile [64 rows][64 k] ----
        if (FIRST && k0 < DIN) {
            // fp32 chars -> bf16 LDS
            #pragma unroll
            for (int i = 0; i < 4; ++i) {
                int r = i * 16 + (tid >> 4);
                int cf = (tid & 15) * 4;
                const float* g = chars + (((size_t)(b0 + r) * TSTEPS + t) * DIN) + k0 + cf;
                float4 v = *(const float4*)g;
                alignas(8) unsigned short pk[4];
                bf16 h0 = __float2bfloat16(v.x), h1v = __float2bfloat16(v.y);
                bf16 h2v = __float2bfloat16(v.z), h3v = __float2bfloat16(v.w);
                pk[0] = *(unsigned short*)&h0;  pk[1] = *(unsigned short*)&h1v;
                pk[2] = *(unsigned short*)&h2v; pk[3] = *(unsigned short*)&h3v;
                *(int2*)(&Alds[r][cf]) = *(int2*)pk;
            }
        } else {
            const bf16* Asrc; int kk0;
            if (FIRST) { Asrc = Hprev; kk0 = k0 - DIN; }
            else       { Asrc = (k0 < 1024) ? A0 : Hprev; kk0 = (k0 < 1024) ? k0 : (k0 - 1024); }
            #pragma unroll
            for (int i = 0; i < 2; ++i) {
                int r = i * 32 + (tid >> 3);
                int c8 = (tid & 7) * 8;
                const bf16* g = Asrc + (size_t)(b0 + r) * H + kk0 + c8;
                *(int4*)(&Alds[r][c8]) = *(const int4*)g;
            }
        }
        // ---- stage B tile: contiguous 16 KB ----
        const bf16* Bg = Bp + ((size_t)kt * NG + n0) * 64;
        #pragma unroll
        for (int i = 0; i < 4; ++i) {
            int off = (i * 256 + tid) * 8;
            *(int4*)(((bf16*)Blds) + off) = *(const int4*)(Bg + off);
        }
        __syncthreads();
        // ---- MFMA: 2 k-steps of 32 ----
        #pragma unroll
        for (int kk = 0; kk < 64; kk += 32) {
            bfrag8 af0 = *(const bfrag8*)(&Alds[mw + (lane & 15)][kk + (lane >> 4) * 8]);
            bfrag8 af1 = *(const bfrag8*)(&Alds[mw + 16 + (lane & 15)][kk + (lane >> 4) * 8]);
            #pragma unroll
            for (int nt = 0; nt < 4; ++nt) {
                bfrag8 bfr = *(const bfrag8*)(&Blds[nw + nt * 16 + (lane & 15)][kk + (lane >> 4) * 8]);
                acc[0][nt] = __builtin_amdgcn_mfma_f32_16x16x32_bf16(af0, bfr, acc[0][nt], 0, 0, 0);
                acc[1][nt] = __builtin_amdgcn_mfma_f32_16x16x32_bf16(af1, bfr, acc[1][nt], 0, 0, 0);
            }
        }
        __syncthreads();
    }

    // ---- epilogue: z -> LDS (C layout: col=lane&15, row=(lane>>4)*4+reg) ----
    #pragma unroll
    for (int mt = 0; mt < 2; ++mt) {
        int rb = mw + mt * 16 + (lane >> 4) * 4;
        #pragma unroll
        for (int nt = 0; nt < 4; ++nt) {
            int col = nw + nt * 16 + (lane & 15);
            #pragma unroll
            for (int r = 0; r < 4; ++r) zlds[rb + r][col] = acc[mt][nt][r];
        }
    }
    __syncthreads();

    // ---- cell update: 64 rows x 32 h-cols, 8 per thread ----
    int j = tid & 31;
    int jg = ntile * 32 + j;
    float bi = bias[jg], bff = bias[H + jg], bg = bias[2 * H + jg], bo = bias[3 * H + jg];
    int r0 = (tid >> 5) * 8;
    #pragma unroll
    for (int rr = 0; rr < 8; ++rr) {
        int r = r0 + rr;
        int b = b0 + r;
        float zi = zlds[r][j] + bi;
        float zf = zlds[r][32 + j] + bff;
        float zg = zlds[r][64 + j] + bg;
        float zo = zlds[r][96 + j] + bo;
        float ig = sigm(zi), fg = sigm(zf), gv = tanh_f(zg), og = sigm(zo);
        size_t idx = (size_t)b * H + jg;
        float c = fg * Cst[idx] + ig * gv;
        Cst[idx] = c;
        float h = og * tanh_f(c);
        Hout[idx] = __float2bfloat16(h);
        if (LAST) {
            if (seqlen[b] - 1 == t) hidden[idx] = h;
        }
    }
}

// ---------------------------------------------------------------------------
// out[b][l] = relu(hidden[b]·Wd[:,l] + bd[l]), 512 blocks x 1 wave
// ---------------------------------------------------------------------------
__global__ void k_final(const float* __restrict__ hidden, const float* __restrict__ Wd,
                        const float* __restrict__ bd, float* __restrict__ out)
{
    int b = blockIdx.x;
    int l = threadIdx.x;
    float p0 = 0.f, p1 = 0.f, p2 = 0.f;
    for (int jj = l; jj < H; jj += 64) {
        float hv = hidden[(size_t)b * H + jj];
        p0 += hv * Wd[jj * 3 + 0];
        p1 += hv * Wd[jj * 3 + 1];
        p2 += hv * Wd[jj * 3 + 2];
    }
    #pragma unroll
    for (int off = 32; off > 0; off >>= 1) {
        p0 += __shfl_down(p0, off);
        p1 += __shfl_down(p1, off);
        p2 += __shfl_down(p2, off);
    }
    if (l == 0) {
        out[b * 3 + 0] = fmaxf(p0 + bd[0], 0.f);
        out[b * 3 + 1] = fmaxf(p1 + bd[1], 0.f);
        out[b * 3 + 2] = fmaxf(p2 + bd[2], 0.f);
    }
}

extern "C" void kernel_launch(void* const* d_in, const int* in_sizes, int n_in,
                              void* d_out, int out_size, void* d_ws, size_t ws_size,
                              hipStream_t stream)
{
    const float* chars = (const float*)d_in[0];
    const int* seqlen  = (const int*)d_in[1];
    const float* W1 = (const float*)d_in[2];
    const float* U1 = (const float*)d_in[3];
    const float* b1 = (const float*)d_in[4];
    const float* W2 = (const float*)d_in[5];
    const float* U2 = (const float*)d_in[6];
    const float* b2 = (const float*)d_in[7];
    const float* Wd = (const float*)d_in[8];
    const float* bd = (const float*)d_in[9];
    float* out = (float*)d_out;

    char* ws = (char*)d_ws;
    size_t off = 0;
    bf16* Bp1 = (bf16*)(ws + off); off += (size_t)20 * NG * 64 * 2;   // 10.0 MB
    bf16* Bp2 = (bf16*)(ws + off); off += (size_t)32 * NG * 64 * 2;   // 16.0 MB
    bf16* h1  = (bf16*)(ws + off); off += (size_t)2 * BATCH * H * 2;  // 2 MB (ping-pong)
    bf16* h2  = (bf16*)(ws + off); off += (size_t)2 * BATCH * H * 2;  // 2 MB
    float* c1 = (float*)(ws + off); off += (size_t)BATCH * H * 4;     // 2 MB
    float* c2 = (float*)(ws + off); off += (size_t)BATCH * H * 4;     // 2 MB
    float* hidden = (float*)(ws + off); off += (size_t)BATCH * H * 4; // 2 MB
    if (ws_size < off) return;  // ~37.75 MB needed

    hipMemsetAsync(h1, 0, (size_t)BATCH * H * 2, stream);
    hipMemsetAsync(h2, 0, (size_t)BATCH * H * 2, stream);
    hipMemsetAsync(c1, 0, (size_t)BATCH * H * 4, stream);
    hipMemsetAsync(c2, 0, (size_t)BATCH * H * 4, stream);

    k_repack<<<dim3(20, 64), 64, 0, stream>>>(W1, U1, Bp1, 256);
    k_repack<<<dim3(32, 64), 64, 0, stream>>>(W2, U2, Bp2, 1024);

    const size_t HS = (size_t)BATCH * H;
    for (int t = 0; t < TSTEPS; ++t) {
        const bf16* h1r = h1 + (size_t)(t & 1) * HS;
        bf16* h1w = h1 + (size_t)((t & 1) ^ 1) * HS;
        const bf16* h2r = h2 + (size_t)(t & 1) * HS;
        bf16* h2w = h2 + (size_t)((t & 1) ^ 1) * HS;
        k_step<true, false><<<dim3(32, 8), 256, 0, stream>>>(
            chars, nullptr, h1r, Bp1, b1, c1, h1w, nullptr, nullptr, t);
        k_step<false, true><<<dim3(32, 8), 256, 0, stream>>>(
            nullptr, h1w, h2r, Bp2, b2, c2, h2w, seqlen, hidden, t);
    }
    k_final<<<512, 64, 0, stream>>>(hidden, Wd, bd, out);
}

// Round 2
// 4181.420 us; speedup vs baseline: 1.9501x; 1.9501x over previous
//
#include <hip/hip_runtime.h>
#include <hip/hip_bf16.h>

// RNNColorbot round 2: swizzled LDS (kills 16-way bank conflicts),
// global_load_lds x16 staging, fused L1(t+1)+L2(t) kernels (2 blocks/CU).

typedef __hip_bfloat16 bf16;
typedef __attribute__((ext_vector_type(8))) short bfrag8;   // 8 bf16 = 4 VGPRs
typedef __attribute__((ext_vector_type(4))) float accf4;    // MFMA accum

#define BATCH 512
#define TSTEPS 128
#define DIN 256
#define H 1024
#define NG 4096   // 4*H gate columns

__device__ __forceinline__ float sigm(float x) { return 1.0f / (1.0f + __expf(-x)); }
__device__ __forceinline__ float tanh_f(float x) {
    float a = fabsf(x);
    float e = __expf(-2.0f * a);
    float t = (1.0f - e) / (1.0f + e);
    return x < 0.0f ? -t : t;
}
__device__ __forceinline__ unsigned short bfr16(float x) {
    bf16 h = __float2bfloat16(x);
    return *(unsigned short*)&h;
}
// async global->LDS, 16B per lane. LDS dest = wave-uniform base + lane*16.
__device__ __forceinline__ void gll16(const void* g, void* l) {
    __builtin_amdgcn_global_load_lds(
        (const __attribute__((address_space(1))) unsigned int*)g,
        (__attribute__((address_space(3))) unsigned int*)l, 16, 0, 0);
}

// ---------------------------------------------------------------------------
// Repack [W;U] (fp32, K x 4096) -> Bp bf16 [KT][4096][64], gate-permuted
// (new col n -> orig ((n>>5)&3)*1024 + (n>>7)*32 + (n&31)) and XOR-swizzled:
// 16B chunk kc (k = kc*8..kc*8+7 within the 64-k segment) of row n stored at
// chunk position kc ^ (n&7). So global layout == desired LDS layout and
// global_load_lds can copy it linearly.
// ---------------------------------------------------------------------------
__global__ void k_repack(const float* __restrict__ W, const float* __restrict__ U,
                         bf16* __restrict__ Bp, int KIN)
{
    __shared__ float tile[64][65];
    int kt = blockIdx.x, nt = blockIdx.y;
    int lane = threadIdx.x;     // 64 threads
    int n = nt * 64 + lane;
    int orig = ((n >> 5) & 3) * 1024 + (n >> 7) * 32 + (n & 31);
    for (int j = 0; j < 64; ++j) {
        int k = kt * 64 + j;
        tile[j][lane] = (k < KIN) ? W[(size_t)k * NG + orig]
                                  : U[(size_t)(k - KIN) * NG + orig];
    }
    __syncthreads();
    for (int p = 0; p < 8; ++p) {
        int nloc = p * 8 + (lane >> 3);
        int nn = nt * 64 + nloc;
        int kc = lane & 7;
        alignas(16) unsigned short pk[8];
        #pragma unroll
        for (int jj = 0; jj < 8; ++jj) pk[jj] = bfr16(tile[kc * 8 + jj][nloc]);
        *(int4*)(Bp + ((size_t)kt * NG + nn) * 64 + ((kc ^ (nn & 7)) << 3)) = *(int4*)pk;
    }
}

// ---------------------------------------------------------------------------
// Fused LSTM step kernel. Each 256-thread block: 64 batch rows x 128 gate
// cols, 4 waves (wave tile 32x64), 16x16x32 bf16 MFMA, swizzled LDS.
// Grid 512 = two jobs (L2 at t, L1 at t+1), 256 blocks each -> 2 blocks/CU.
// ---------------------------------------------------------------------------
struct StepJob {
    const float* Xf;      // L1 only: fp32 x source (chars + t*DIN), else null
    const bf16* A0;       // first-K bf16 source (L2: h1[t]); pre-swizzled
    const bf16* A1;       // recurrent h-prev source; pre-swizzled
    const bf16* Bp;       // weights (gate-permuted + swizzled)
    const float* bias;    // [4096] original gate order
    float* C;             // fp32 cell state [512][1024]
    bf16* Hout;           // h output, written SWIZZLED
    float* hidden;        // L2 only: fp32 gather target (linear layout)
    const int* seqlen;    // L2 only
    int xstride;          // elems per row of Xf
    int ksplit;           // 256 (L1) / 1024 (L2)
    int KT;               // 20 / 32
    int t;
};

__global__ __launch_bounds__(256, 2) void k_step(StepJob j0, StepJob j1)
{
    __shared__ __align__(16) bf16 Alds[64 * 64];    // 8 KB, swizzled
    __shared__ __align__(16) bf16 Blds[128 * 64];   // 16 KB, swizzled
    __shared__ float zlds[64][129];                 // 32.25 KB epilogue

    const StepJob jb = (blockIdx.x >> 8) ? j1 : j0;
    int bi = blockIdx.x & 255;
    int tid = threadIdx.x;
    int wv = tid >> 6, lane = tid & 63;
    int ntile = bi & 31;                // consistent ntile -> XCD mapping
    int b0 = (bi >> 5) * 64;
    int n0 = ntile * 128;
    int mw = (wv & 1) * 32;
    int nw = (wv >> 1) * 64;

    const accf4 zero4 = {0.f, 0.f, 0.f, 0.f};
    accf4 acc[2][4];
    #pragma unroll
    for (int i = 0; i < 2; ++i)
        #pragma unroll
        for (int j = 0; j < 4; ++j) acc[i][j] = zero4;

    for (int kt = 0; kt < jb.KT; ++kt) {
        int k0 = kt << 6;
        // ---- stage A tile [64 rows][64 k] (swizzled) ----
        if (jb.Xf && k0 < jb.ksplit) {
            // fp32 -> bf16 convert path (L1 x-tiles only; 4 of 20 kt)
            #pragma unroll
            for (int uu = 0; uu < 2; ++uu) {
                int u = uu * 256 + tid;            // chunk id 0..511
                int r = u >> 3;                    // row
                int pos = u & 7;                   // swizzled chunk position
                int kc = pos ^ (r & 7);            // logical k-chunk
                const float* src = jb.Xf + (size_t)(b0 + r) * jb.xstride + k0 + kc * 8;
                float4 va = *(const float4*)src;
                float4 vb = *(const float4*)(src + 4);
                alignas(16) unsigned short pk[8];
                pk[0] = bfr16(va.x); pk[1] = bfr16(va.y);
                pk[2] = bfr16(va.z); pk[3] = bfr16(va.w);
                pk[4] = bfr16(vb.x); pk[5] = bfr16(vb.y);
                pk[6] = bfr16(vb.z); pk[7] = bfr16(vb.w);
                *(int4*)((char*)Alds + u * 16) = *(int4*)pk;
            }
        } else {
            const bf16* Asrc; int kk0;
            if (k0 < jb.ksplit) { Asrc = jb.A0; kk0 = k0; }
            else                { Asrc = jb.A1; kk0 = k0 - jb.ksplit; }
            // source already swizzled -> linear 128B-per-row copy
            #pragma unroll
            for (int cc = 0; cc < 2; ++cc) {
                int ob = wv * 2048 + cc * 1024;
                int o = ob + lane * 16;
                int r = o >> 7;
                const char* g = (const char*)(Asrc + (size_t)(b0 + r) * H + kk0) + (o & 127);
                gll16(g, (char*)Alds + ob);
            }
        }
        // ---- stage B tile: contiguous 16 KB (pre-swizzled in global) ----
        const char* Bg = (const char*)(jb.Bp + ((size_t)kt * NG + n0) * 64);
        #pragma unroll
        for (int cc = 0; cc < 4; ++cc) {
            int ob = wv * 4096 + cc * 1024;
            gll16(Bg + ob + lane * 16, (char*)Blds + ob);
        }
        __syncthreads();
        // ---- MFMA: 2 k-steps of 32, swizzle-decoded fragment reads ----
        #pragma unroll
        for (int kk = 0; kk < 64; kk += 32) {
            int lc = (kk >> 3) + (lane >> 4);         // logical chunk 0..7
            int ra = mw + (lane & 15);
            int pa = (lc ^ (ra & 7)) << 3;            // (ra+16)&7 == ra&7
            bfrag8 af0 = *(const bfrag8*)(Alds + ra * 64 + pa);
            bfrag8 af1 = *(const bfrag8*)(Alds + (ra + 16) * 64 + pa);
            #pragma unroll
            for (int nt = 0; nt < 4; ++nt) {
                int nn = nw + nt * 16 + (lane & 15);
                bfrag8 bfv = *(const bfrag8*)(Blds + nn * 64 + ((lc ^ (nn & 7)) << 3));
                acc[0][nt] = __builtin_amdgcn_mfma_f32_16x16x32_bf16(af0, bfv, acc[0][nt], 0, 0, 0);
                acc[1][nt] = __builtin_amdgcn_mfma_f32_16x16x32_bf16(af1, bfv, acc[1][nt], 0, 0, 0);
            }
        }
        __syncthreads();
    }

    // ---- epilogue: z -> LDS (C layout: col=lane&15, row=(lane>>4)*4+reg) ----
    #pragma unroll
    for (int mt = 0; mt < 2; ++mt) {
        int rb = mw + mt * 16 + (lane >> 4) * 4;
        #pragma unroll
        for (int nt = 0; nt < 4; ++nt) {
            int col = nw + nt * 16 + (lane & 15);
            #pragma unroll
            for (int r = 0; r < 4; ++r) zlds[rb + r][col] = acc[mt][nt][r];
        }
    }
    __syncthreads();

    // ---- cell update: 64 rows x 32 h-cols ----
    int j = tid & 31;
    int jg = ntile * 32 + j;
    float bi_ = jb.bias[jg], bf_ = jb.bias[H + jg];
    float bg_ = jb.bias[2 * H + jg], bo_ = jb.bias[3 * H + jg];
    int seg = jg & ~63;
    int kc = (jg >> 3) & 7;
    int jl = jg & 7;
    int r0 = (tid >> 5) * 8;
    #pragma unroll
    for (int rr = 0; rr < 8; ++rr) {
        int r = r0 + rr;
        int b = b0 + r;
        float zi = zlds[r][j]      + bi_;
        float zf = zlds[r][32 + j] + bf_;
        float zg = zlds[r][64 + j] + bg_;
        float zo = zlds[r][96 + j] + bo_;
        float ig = sigm(zi), fg = sigm(zf), gv = tanh_f(zg), og = sigm(zo);
        size_t ci = (size_t)b * H + jg;
        float c = fg * jb.C[ci] + ig * gv;
        jb.C[ci] = c;
        float h = og * tanh_f(c);
        // store h pre-swizzled (it is only ever read as an A-tile)
        int off = seg + ((kc ^ (b & 7)) << 3) + jl;
        jb.Hout[(size_t)b * H + off] = __float2bfloat16(h);
        if (jb.hidden) {
            if (jb.seqlen[b] - 1 == jb.t) jb.hidden[ci] = h;   // linear layout
        }
    }
}

// ---------------------------------------------------------------------------
// out[b][l] = relu(hidden[b]·Wd[:,l] + bd[l]), 512 blocks x 1 wave
// ---------------------------------------------------------------------------
__global__ void k_final(const float* __restrict__ hidden, const float* __restrict__ Wd,
                        const float* __restrict__ bd, float* __restrict__ out)
{
    int b = blockIdx.x;
    int l = threadIdx.x;
    float p0 = 0.f, p1 = 0.f, p2 = 0.f;
    for (int jj = l; jj < H; jj += 64) {
        float hv = hidden[(size_t)b * H + jj];
        p0 += hv * Wd[jj * 3 + 0];
        p1 += hv * Wd[jj * 3 + 1];
        p2 += hv * Wd[jj * 3 + 2];
    }
    #pragma unroll
    for (int off = 32; off > 0; off >>= 1) {
        p0 += __shfl_down(p0, off);
        p1 += __shfl_down(p1, off);
        p2 += __shfl_down(p2, off);
    }
    if (l == 0) {
        out[b * 3 + 0] = fmaxf(p0 + bd[0], 0.f);
        out[b * 3 + 1] = fmaxf(p1 + bd[1], 0.f);
        out[b * 3 + 2] = fmaxf(p2 + bd[2], 0.f);
    }
}

extern "C" void kernel_launch(void* const* d_in, const int* in_sizes, int n_in,
                              void* d_out, int out_size, void* d_ws, size_t ws_size,
                              hipStream_t stream)
{
    const float* chars = (const float*)d_in[0];
    const int* seqlen  = (const int*)d_in[1];
    const float* W1 = (const float*)d_in[2];
    const float* U1 = (const float*)d_in[3];
    const float* b1 = (const float*)d_in[4];
    const float* W2 = (const float*)d_in[5];
    const float* U2 = (const float*)d_in[6];
    const float* b2 = (const float*)d_in[7];
    const float* Wd = (const float*)d_in[8];
    const float* bd = (const float*)d_in[9];
    float* out = (float*)d_out;

    char* ws = (char*)d_ws;
    size_t off = 0;
    bf16* Bp1 = (bf16*)(ws + off); off += (size_t)20 * NG * 64 * 2;   // 10.0 MB
    bf16* Bp2 = (bf16*)(ws + off); off += (size_t)32 * NG * 64 * 2;   // 16.0 MB
    bf16* h1  = (bf16*)(ws + off); off += (size_t)2 * BATCH * H * 2;  // 2 MB ping-pong
    bf16* h2  = (bf16*)(ws + off); off += (size_t)2 * BATCH * H * 2;  // 2 MB
    float* c1 = (float*)(ws + off); off += (size_t)BATCH * H * 4;     // 2 MB
    float* c2 = (float*)(ws + off); off += (size_t)BATCH * H * 4;     // 2 MB
    float* hidden = (float*)(ws + off); off += (size_t)BATCH * H * 4; // 2 MB
    if (ws_size < off) return;  // ~37.75 MB needed

    hipMemsetAsync(h1, 0, (size_t)2 * BATCH * H * 2, stream);
    hipMemsetAsync(h2, 0, (size_t)2 * BATCH * H * 2, stream);
    hipMemsetAsync(c1, 0, (size_t)BATCH * H * 4, stream);
    hipMemsetAsync(c2, 0, (size_t)BATCH * H * 4, stream);

    k_repack<<<dim3(20, 64), 64, 0, stream>>>(W1, U1, Bp1, 256);
    k_repack<<<dim3(32, 64), 64, 0, stream>>>(W2, U2, Bp2, 1024);

    const size_t HS = (size_t)BATCH * H;

    auto mkL1 = [&](int s) {
        StepJob J;
        J.Xf = chars + (size_t)s * DIN;  J.xstride = TSTEPS * DIN;
        J.A0 = nullptr;
        J.A1 = h1 + (size_t)((s + 1) & 1) * HS;   // h1[s-1]
        J.Bp = Bp1; J.bias = b1; J.C = c1;
        J.Hout = h1 + (size_t)(s & 1) * HS;       // h1[s]
        J.hidden = nullptr; J.seqlen = nullptr;
        J.ksplit = 256; J.KT = 20; J.t = s;
        return J;
    };
    auto mkL2 = [&](int s) {
        StepJob J;
        J.Xf = nullptr; J.xstride = 0;
        J.A0 = h1 + (size_t)(s & 1) * HS;         // h1[s]
        J.A1 = h2 + (size_t)((s + 1) & 1) * HS;   // h2[s-1]
        J.Bp = Bp2; J.bias = b2; J.C = c2;
        J.Hout = h2 + (size_t)(s & 1) * HS;       // h2[s]
        J.hidden = hidden; J.seqlen = seqlen;
        J.ksplit = 1024; J.KT = 32; J.t = s;
        return J;
    };

    StepJob first = mkL1(0);
    k_step<<<256, 256, 0, stream>>>(first, first);
    for (int t = 0; t < TSTEPS - 1; ++t) {
        k_step<<<512, 256, 0, stream>>>(mkL2(t), mkL1(t + 1));
    }
    StepJob last = mkL2(TSTEPS - 1);
    k_step<<<256, 256, 0, stream>>>(last, last);
    k_final<<<512, 64, 0, stream>>>(hidden, Wd, bd, out);
}

// Round 3
// 3660.184 us; speedup vs baseline: 2.2278x; 1.1424x over previous
//
#include <hip/hip_runtime.h>
#include <hip/hip_bf16.h>

// RNNColorbot round 3: BK=128 (half the barrier rounds), gate-16 column
// permutation so the LSTM cell update is fully register-resident (no z
// exchange through LDS), swizzled LDS + global_load_lds x16 staging.

typedef __hip_bfloat16 bf16;
typedef __attribute__((ext_vector_type(8))) short bfrag8;   // 8 bf16 = 4 VGPRs
typedef __attribute__((ext_vector_type(4))) float accf4;    // MFMA accum

#define BATCH 512
#define TSTEPS 128
#define DIN 256
#define H 1024
#define NG 4096   // 4*H gate columns

__device__ __forceinline__ float sigm(float x) { return 1.0f / (1.0f + __expf(-x)); }
__device__ __forceinline__ float tanh_f(float x) {
    float a = fabsf(x);
    float e = __expf(-2.0f * a);
    float t = (1.0f - e) / (1.0f + e);
    return x < 0.0f ? -t : t;
}
__device__ __forceinline__ unsigned short bfr16(float x) {
    bf16 h = __float2bfloat16(x);
    return *(unsigned short*)&h;
}
// async global->LDS, 16B/lane. HW dest = wave-uniform LDS base + lane*16.
__device__ __forceinline__ void gll16(const void* g, void* l) {
    __builtin_amdgcn_global_load_lds(
        (const __attribute__((address_space(1))) unsigned int*)g,
        (__attribute__((address_space(3))) unsigned int*)l, 16, 0, 0);
}

// ---------------------------------------------------------------------------
// Repack [W;U] (fp32, K x 4096) -> Bp bf16 [KT][4096][128], gate-16 permuted:
//   new col n -> orig ((n>>4)&3)*1024 + (n>>7)*32 + ((n>>6)&1)*16 + (n&15)
// i.e. each 64-col wave tile = gates [i|f|g|o] x 16 h-cols. XOR-swizzled in
// 16B chunks: chunk kc of row n stored at position kc ^ (n&7) (bit3 kept),
// so global layout == LDS layout and global_load_lds copies linearly.
// ---------------------------------------------------------------------------
__global__ void k_repack(const float* __restrict__ W, const float* __restrict__ U,
                         bf16* __restrict__ Bp, int KIN)
{
    __shared__ float tile[128][65];
    int kt = blockIdx.x, nt = blockIdx.y;
    int lane = threadIdx.x;     // 64 threads
    int n = nt * 64 + lane;
    int orig = ((n >> 4) & 3) * 1024 + (n >> 7) * 32 + ((n >> 6) & 1) * 16 + (n & 15);
    for (int j = 0; j < 128; ++j) {
        int k = kt * 128 + j;
        tile[j][lane] = (k < KIN) ? W[(size_t)k * NG + orig]
                                  : U[(size_t)(k - KIN) * NG + orig];
    }
    __syncthreads();
    for (int u = 0; u < 16; ++u) {
        int cid = u * 64 + lane;           // 1024 chunks
        int nloc = cid >> 4;
        int pos = cid & 15;
        int nn = nt * 64 + nloc;
        int kc = pos ^ (nn & 7);           // logical chunk stored here
        alignas(16) unsigned short pk[8];
        #pragma unroll
        for (int jj = 0; jj < 8; ++jj) pk[jj] = bfr16(tile[kc * 8 + jj][nloc]);
        *(int4*)(Bp + ((size_t)kt * NG + nn) * 128 + pos * 8) = *(int4*)pk;
    }
}

// ---------------------------------------------------------------------------
// Fused LSTM step kernel. 256 threads: 64 batch rows x 128 gate cols, BK=128,
// 4 waves (wave tile 32x64 = all 4 gates for 16 h-cols), 16x16x32 bf16 MFMA.
// Cell update is register-resident (gates land in acc[mt][gate][reg]).
// Grid 512 = two jobs (L2 at t, L1 at t+1) -> 2 blocks/CU.
// ---------------------------------------------------------------------------
struct StepJob {
    const float* Xf;      // L1: fp32 x source (chars + t*DIN), else null
    const bf16* A0;       // first-K bf16 source (L2: h1[t]); swizzled
    const bf16* A1;       // recurrent h-prev source; swizzled
    const bf16* Bp;       // weights (gate-16 permuted + swizzled)
    const float* bias;    // [4096] original gate order
    float* C;             // fp32 cell state [512][1024]
    bf16* Hout;           // h output, written SWIZZLED
    float* hidden;        // L2: fp32 gather target (linear)
    const int* seqlen;    // L2
    int xstride;          // elems per row of Xf
    int ksplit;           // 256 (L1) / 1024 (L2)
    int KT;               // 10 / 16 rounds of BK=128
    int t;
};

__global__ __launch_bounds__(256, 2) void k_step(StepJob j0, StepJob j1)
{
    __shared__ __align__(16) bf16 Alds[64 * 128];    // 16 KB, swizzled
    __shared__ __align__(16) bf16 Blds[128 * 128];   // 32 KB, swizzled

    const StepJob jb = (blockIdx.x >> 8) ? j1 : j0;
    int bi = blockIdx.x & 255;
    int tid = threadIdx.x;
    int wv = tid >> 6, lane = tid & 63;
    int ntile = bi & 31;                // consistent ntile -> XCD mapping
    int b0 = (bi >> 5) * 64;
    int n0 = ntile * 128;
    int mw = (wv & 1) * 32;
    int nw = (wv >> 1) * 64;
    int c = lane & 15, q = lane >> 4;

    const accf4 zero4 = {0.f, 0.f, 0.f, 0.f};
    accf4 acc[2][4];
    #pragma unroll
    for (int i = 0; i < 2; ++i)
        #pragma unroll
        for (int j = 0; j < 4; ++j) acc[i][j] = zero4;

    for (int kt = 0; kt < jb.KT; ++kt) {
        int k0 = kt << 7;
        // ---- stage A tile [64 rows][128 k] (swizzled) ----
        if (jb.Xf && k0 < jb.ksplit) {
            // fp32 -> bf16 convert path (L1 x-tiles; kt 0..1)
            #pragma unroll
            for (int uu = 0; uu < 4; ++uu) {
                int u = uu * 256 + tid;            // chunk id 0..1023
                int r = u >> 4;                    // row
                int pos = u & 15;                  // swizzled position
                int kc = pos ^ (r & 7);            // logical k-chunk
                const float* src = jb.Xf + (size_t)(b0 + r) * jb.xstride + k0 + kc * 8;
                float4 va = *(const float4*)src;
                float4 vb = *(const float4*)(src + 4);
                alignas(16) unsigned short pk[8];
                pk[0] = bfr16(va.x); pk[1] = bfr16(va.y);
                pk[2] = bfr16(va.z); pk[3] = bfr16(va.w);
                pk[4] = bfr16(vb.x); pk[5] = bfr16(vb.y);
                pk[6] = bfr16(vb.z); pk[7] = bfr16(vb.w);
                *(int4*)((char*)Alds + u * 16) = *(int4*)pk;
            }
        } else {
            const bf16* Asrc; int kk0;
            if (k0 < jb.ksplit) { Asrc = jb.A0; kk0 = k0; }
            else                { Asrc = jb.A1; kk0 = k0 - jb.ksplit; }
            // source already swizzled -> linear 256B-per-row copy
            #pragma unroll
            for (int cc = 0; cc < 4; ++cc) {
                int ob = wv * 4096 + cc * 1024;
                int o = ob + lane * 16;
                int r = o >> 8;
                const char* g = (const char*)Asrc + (size_t)(b0 + r) * (H * 2) + kk0 * 2 + (o & 255);
                gll16(g, (char*)Alds + ob);
            }
        }
        // ---- stage B tile: contiguous 32 KB (pre-swizzled in global) ----
        const char* Bg = (const char*)jb.Bp + ((size_t)kt * NG + n0) * 256;
        #pragma unroll
        for (int cc = 0; cc < 8; ++cc) {
            int ob = wv * 8192 + cc * 1024;
            gll16(Bg + ob + lane * 16, (char*)Blds + ob);
        }
        __syncthreads();
        // ---- MFMA: 4 k-steps of 32, swizzle-decoded fragment reads ----
        #pragma unroll
        for (int kk = 0; kk < 128; kk += 32) {
            int kc = (kk >> 3) + q;                  // logical chunk 0..15
            int ra = mw + c;
            int pa = (kc ^ (ra & 7)) << 3;           // (ra+16)&7 == ra&7
            bfrag8 af0 = *(const bfrag8*)(Alds + ra * 128 + pa);
            bfrag8 af1 = *(const bfrag8*)(Alds + (ra + 16) * 128 + pa);
            #pragma unroll
            for (int nt = 0; nt < 4; ++nt) {
                int nn = nw + nt * 16 + c;
                bfrag8 bfv = *(const bfrag8*)(Blds + nn * 128 + ((kc ^ (nn & 7)) << 3));
                acc[0][nt] = __builtin_amdgcn_mfma_f32_16x16x32_bf16(af0, bfv, acc[0][nt], 0, 0, 0);
                acc[1][nt] = __builtin_amdgcn_mfma_f32_16x16x32_bf16(af1, bfv, acc[1][nt], 0, 0, 0);
            }
        }
        __syncthreads();
    }

    // ---- register-resident cell update ----
    // acc[mt][gate][reg]: row = mw+mt*16+q*4+reg, hcol = ntile*32+(wv>>1)*16+c
    int hcol = ntile * 32 + (wv >> 1) * 16 + c;
    float bi_ = jb.bias[hcol],         bf_ = jb.bias[H + hcol];
    float bg_ = jb.bias[2 * H + hcol], bo_ = jb.bias[3 * H + hcol];
    int seg = hcol & ~127;
    int kc_ = (hcol & 127) >> 3;
    int jl = hcol & 7;
    #pragma unroll
    for (int mt = 0; mt < 2; ++mt) {
        #pragma unroll
        for (int reg = 0; reg < 4; ++reg) {
            int b = b0 + mw + mt * 16 + q * 4 + reg;
            float ig = sigm(acc[mt][0][reg] + bi_);
            float fg = sigm(acc[mt][1][reg] + bf_);
            float gv = tanh_f(acc[mt][2][reg] + bg_);
            float og = sigm(acc[mt][3][reg] + bo_);
            size_t ci = (size_t)b * H + hcol;
            float cv = fg * jb.C[ci] + ig * gv;
            jb.C[ci] = cv;
            float h = og * tanh_f(cv);
            // store h pre-swizzled (only ever read as an A-tile)
            jb.Hout[(size_t)b * H + seg + ((kc_ ^ (b & 7)) << 3) + jl] = __float2bfloat16(h);
            if (jb.hidden) {
                if (jb.seqlen[b] - 1 == jb.t) jb.hidden[ci] = h;   // linear
            }
        }
    }
}

// ---------------------------------------------------------------------------
// out[b][l] = relu(hidden[b]·Wd[:,l] + bd[l]), 512 blocks x 1 wave
// ---------------------------------------------------------------------------
__global__ void k_final(const float* __restrict__ hidden, const float* __restrict__ Wd,
                        const float* __restrict__ bd, float* __restrict__ out)
{
    int b = blockIdx.x;
    int l = threadIdx.x;
    float p0 = 0.f, p1 = 0.f, p2 = 0.f;
    for (int jj = l; jj < H; jj += 64) {
        float hv = hidden[(size_t)b * H + jj];
        p0 += hv * Wd[jj * 3 + 0];
        p1 += hv * Wd[jj * 3 + 1];
        p2 += hv * Wd[jj * 3 + 2];
    }
    #pragma unroll
    for (int off = 32; off > 0; off >>= 1) {
        p0 += __shfl_down(p0, off);
        p1 += __shfl_down(p1, off);
        p2 += __shfl_down(p2, off);
    }
    if (l == 0) {
        out[b * 3 + 0] = fmaxf(p0 + bd[0], 0.f);
        out[b * 3 + 1] = fmaxf(p1 + bd[1], 0.f);
        out[b * 3 + 2] = fmaxf(p2 + bd[2], 0.f);
    }
}

extern "C" void kernel_launch(void* const* d_in, const int* in_sizes, int n_in,
                              void* d_out, int out_size, void* d_ws, size_t ws_size,
                              hipStream_t stream)
{
    const float* chars = (const float*)d_in[0];
    const int* seqlen  = (const int*)d_in[1];
    const float* W1 = (const float*)d_in[2];
    const float* U1 = (const float*)d_in[3];
    const float* b1 = (const float*)d_in[4];
    const float* W2 = (const float*)d_in[5];
    const float* U2 = (const float*)d_in[6];
    const float* b2 = (const float*)d_in[7];
    const float* Wd = (const float*)d_in[8];
    const float* bd = (const float*)d_in[9];
    float* out = (float*)d_out;

    char* ws = (char*)d_ws;
    size_t off = 0;
    bf16* Bp1 = (bf16*)(ws + off); off += (size_t)10 * NG * 128 * 2;  // 10.0 MB
    bf16* Bp2 = (bf16*)(ws + off); off += (size_t)16 * NG * 128 * 2;  // 16.0 MB
    bf16* h1  = (bf16*)(ws + off); off += (size_t)2 * BATCH * H * 2;  // 2 MB ping-pong
    bf16* h2  = (bf16*)(ws + off); off += (size_t)2 * BATCH * H * 2;  // 2 MB
    float* c1 = (float*)(ws + off); off += (size_t)BATCH * H * 4;     // 2 MB
    float* c2 = (float*)(ws + off); off += (size_t)BATCH * H * 4;     // 2 MB
    float* hidden = (float*)(ws + off); off += (size_t)BATCH * H * 4; // 2 MB
    if (ws_size < off) return;  // ~36 MB needed

    hipMemsetAsync(h1, 0, (size_t)2 * BATCH * H * 2, stream);
    hipMemsetAsync(h2, 0, (size_t)2 * BATCH * H * 2, stream);
    hipMemsetAsync(c1, 0, (size_t)BATCH * H * 4, stream);
    hipMemsetAsync(c2, 0, (size_t)BATCH * H * 4, stream);

    k_repack<<<dim3(10, 64), 64, 0, stream>>>(W1, U1, Bp1, 256);
    k_repack<<<dim3(16, 64), 64, 0, stream>>>(W2, U2, Bp2, 1024);

    const size_t HS = (size_t)BATCH * H;

    auto mkL1 = [&](int s) {
        StepJob J;
        J.Xf = chars + (size_t)s * DIN;  J.xstride = TSTEPS * DIN;
        J.A0 = nullptr;
        J.A1 = h1 + (size_t)((s + 1) & 1) * HS;   // h1[s-1]
        J.Bp = Bp1; J.bias = b1; J.C = c1;
        J.Hout = h1 + (size_t)(s & 1) * HS;       // h1[s]
        J.hidden = nullptr; J.seqlen = nullptr;
        J.ksplit = 256; J.KT = 10; J.t = s;
        return J;
    };
    auto mkL2 = [&](int s) {
        StepJob J;
        J.Xf = nullptr; J.xstride = 0;
        J.A0 = h1 + (size_t)(s & 1) * HS;         // h1[s]
        J.A1 = h2 + (size_t)((s + 1) & 1) * HS;   // h2[s-1]
        J.Bp = Bp2; J.bias = b2; J.C = c2;
        J.Hout = h2 + (size_t)(s & 1) * HS;       // h2[s]
        J.hidden = hidden; J.seqlen = seqlen;
        J.ksplit = 1024; J.KT = 16; J.t = s;
        return J;
    };

    StepJob first = mkL1(0);
    k_step<<<256, 256, 0, stream>>>(first, first);
    for (int t = 0; t < TSTEPS - 1; ++t) {
        k_step<<<512, 256, 0, stream>>>(mkL2(t), mkL1(t + 1));
    }
    StepJob last = mkL2(TSTEPS - 1);
    k_step<<<256, 256, 0, stream>>>(last, last);
    k_final<<<512, 64, 0, stream>>>(hidden, Wd, bd, out);
}